// Round 4
// baseline (623.681 us; speedup 1.0000x reference)
//
#include <hip/hip_runtime.h>

// HashGridEncoding: N=2^20 points, 12 levels, T=2^19 entries/level, F=2.
//
// Round-4: sorted gather kept (proven -35% on gather); permutation machinery
// slimmed:
//   K1 key_hist : res-32 bucket histogram (atomics)
//   K2 scan     : exclusive prefix sum over 32768 buckets (1 block)
//   K3 scatter  : xs4[s] = float4(coords) -- ONE aligned 16B scattered store
//                 (was 3x4B with line straddles); o2s[n]=s coalesced
//   K4 gather   : level-major over sorted pts, reads xs4 coalesced, writes
//                 ws tiled [s/16][l][16] dwords -> 4 full 64B lines per
//                 wave-level, a point's 12 dwords inside one 768B tile
//   K5 finish   : thread n: s=o2s[n] (coalesced), 12 scattered dword reads
//                 confined to one 768B L3-resident tile, out[n] coalesced.
// retile kernel deleted (-96MB round-trip, -1 launch).
// Per-point arithmetic identical to the proven kernel -> same absmax.

constexpr int NPTS     = 1 << 20;
constexpr int NLEVELS  = 12;
constexpr unsigned T     = 1u << 19;
constexpr unsigned TMASK = T - 1u;
constexpr unsigned P1 = 2654435761u;
constexpr unsigned P2 = 805459861u;

constexpr int NBUCK = 32 * 32 * 32;   // res-32 spatial buckets

constexpr float WS_SCALE     = 16384.0f;          // 2^14, exact
constexpr float WS_INV_SCALE = 1.0f / 16384.0f;

typedef float    vfloat2 __attribute__((ext_vector_type(2)));
typedef float    vfloat4 __attribute__((ext_vector_type(4)));
typedef _Float16 vhalf2  __attribute__((ext_vector_type(2)));

// floor(16 * 1.38^l) for l=0..11 (verified in fp64)
__constant__ float c_res[NLEVELS] = {16.f, 22.f, 30.f, 42.f, 58.f, 80.f,
                                     110.f, 152.f, 210.f, 290.f, 400.f, 553.f};

__device__ __forceinline__ float2 encode_one_level(
    float px, float py, float pz, float r, const float2* __restrict__ tab)
{
    const float xs = px * r, ys = py * r, zs = pz * r;
    const float xf = floorf(xs), yf = floorf(ys), zf = floorf(zs);
    const float wx = xs - xf, wy = ys - yf, wz = zs - zf;
    const unsigned xi = (unsigned)xf, yi = (unsigned)yf, zi = (unsigned)zf;

    unsigned Y[4];
#pragma unroll
    for (int j = 0; j < 4; ++j) {
        const unsigned oy = j & 1u, oz = (j >> 1) & 1u;
        Y[j] = ((yi + oy) * P1) ^ ((zi + oz) * P2);
    }

    float2 f[8];
    if ((xi & 1u) == 0u) {
        // even xi: corners (ox=0 -> h, ox=1 -> h^1) share one 16B-aligned pair
#pragma unroll
        for (int j = 0; j < 4; ++j) {
            const unsigned h = (xi ^ Y[j]) & TMASK;
            const vfloat4 q = *reinterpret_cast<const vfloat4*>(
                tab + (h & ~1u));
            const bool hi = (h & 1u) != 0u;
            const float2 e_lo = make_float2(q.x, q.y);
            const float2 e_hi = make_float2(q.z, q.w);
            f[2 * j + 0] = hi ? e_hi : e_lo;
            f[2 * j + 1] = hi ? e_lo : e_hi;
        }
    } else {
#pragma unroll
        for (int j = 0; j < 4; ++j) {
            const unsigned h0 = (xi ^ Y[j]) & TMASK;
            const unsigned h1 = ((xi + 1u) ^ Y[j]) & TMASK;
            f[2 * j + 0] = tab[h0];
            f[2 * j + 1] = tab[h1];
        }
    }

    float f0 = 0.f, f1 = 0.f;
#pragma unroll
    for (int c = 0; c < 8; ++c) {
        const unsigned ox = c & 1u, oy = (c >> 1) & 1u, oz = (c >> 2) & 1u;
        const float w = (ox ? wx : 1.f - wx) *
                        (oy ? wy : 1.f - wy) *
                        (oz ? wz : 1.f - wz);
        f0 += w * f[c].x;
        f1 += w * f[c].y;
    }
    return make_float2(f0, f1);
}

__device__ __forceinline__ unsigned bucket_of(float px, float py, float pz)
{
    const unsigned bx = min((unsigned)(px * 32.0f), 31u);
    const unsigned by = min((unsigned)(py * 32.0f), 31u);
    const unsigned bz = min((unsigned)(pz * 32.0f), 31u);
    return (bx << 10) | (by << 5) | bz;
}

// ---------------- sorted-path kernels ----------------

__global__ __launch_bounds__(256)
void key_hist_kernel(const float* __restrict__ x,
                     unsigned* __restrict__ hist)
{
    const int n = blockIdx.x * 256 + threadIdx.x;
    const unsigned k = bucket_of(x[3 * n + 0], x[3 * n + 1], x[3 * n + 2]);
    atomicAdd(&hist[k], 1u);
}

// Exclusive prefix sum of 32768 bucket counts. Single block, 1024 thr x 32.
__global__ __launch_bounds__(1024)
void scan_kernel(const unsigned* __restrict__ hist,
                 unsigned* __restrict__ cursor)
{
    __shared__ unsigned sblk[1024];
    const int t = threadIdx.x;
    const int base = t * 32;

    unsigned v[32];
    unsigned sum = 0;
#pragma unroll
    for (int i = 0; i < 32; ++i) {
        v[i] = hist[base + i];
        sum += v[i];
    }
    sblk[t] = sum;
    __syncthreads();

    for (int off = 1; off < 1024; off <<= 1) {
        const unsigned add = (t >= off) ? sblk[t - off] : 0u;
        __syncthreads();
        sblk[t] += add;
        __syncthreads();
    }
    unsigned acc = sblk[t] - sum;
#pragma unroll
    for (int i = 0; i < 32; ++i) {
        cursor[base + i] = acc;
        acc += v[i];
    }
}

// Scatter to sorted order: ONE aligned 16B scattered store per point.
// Slot order within a bucket is race-assigned, but each point's output
// depends only on its own coords -> deterministic final output.
__global__ __launch_bounds__(256)
void scatter_kernel(const float* __restrict__ x,
                    unsigned* __restrict__ cursor,
                    vfloat4* __restrict__ xs4,
                    unsigned* __restrict__ o2s)
{
    const int n = blockIdx.x * 256 + threadIdx.x;
    const float px = x[3 * n + 0];
    const float py = x[3 * n + 1];
    const float pz = x[3 * n + 2];
    const unsigned k = bucket_of(px, py, pz);
    const unsigned s = atomicAdd(&cursor[k], 1u);
    xs4[s] = vfloat4{px, py, pz, 0.f};   // one line-touch, no straddle
    o2s[n] = s;                          // coalesced
}

// Level-major gather over SORTED points; grid (NPTS/256, NLEVELS).
// ws tiling: dword idx = (s/16)*192 + l*16 + (s%16)  [192 dw = 768B tile]
// -> per wave per level: 4 full 64B lines, fully coalesced; a point's 12
// dwords sit at stride 16 inside one 768B tile (finish reads them there).
__global__ __launch_bounds__(256, 8)
void gather_kernel(const vfloat4* __restrict__ xs4,
                   const float* __restrict__ tables,
                   unsigned* __restrict__ ws_dw)
{
    const int s = blockIdx.x * 256 + threadIdx.x;
    const int l = blockIdx.y;

    const vfloat4 p = xs4[s];

    const float2* __restrict__ tab =
        reinterpret_cast<const float2*>(tables) + (size_t)l * T;

    const float2 f = encode_one_level(p.x, p.y, p.z, c_res[l], tab);
    const vhalf2 h = {(_Float16)(f.x * WS_SCALE), (_Float16)(f.y * WS_SCALE)};
    const size_t idx = (size_t)(s >> 4) * 192 + (unsigned)l * 16u + (s & 15);
    ws_dw[idx] = __builtin_bit_cast(unsigned, h);
}

// finish-by-original: coalesced o2s read; 12 scattered dword reads confined
// to one 768B L3-resident tile; fully coalesced nontemporal out write.
__global__ __launch_bounds__(256)
void finish_kernel(const unsigned* __restrict__ ws_dw,
                   const unsigned* __restrict__ o2s,
                   float* __restrict__ out)
{
    const int n = blockIdx.x * 256 + threadIdx.x;
    const unsigned s = o2s[n];

    const unsigned* __restrict__ rec =
        ws_dw + (size_t)(s >> 4) * 192 + (s & 15u);

    float vals[24];
#pragma unroll
    for (int l = 0; l < NLEVELS; ++l) {
        const unsigned u = __builtin_nontemporal_load(rec + l * 16);
        const vhalf2 h = __builtin_bit_cast(vhalf2, u);
        vals[2 * l + 0] = (float)h.x * WS_INV_SCALE;
        vals[2 * l + 1] = (float)h.y * WS_INV_SCALE;
    }

    float* __restrict__ op = out + (size_t)n * 24;
#pragma unroll
    for (int i = 0; i < 6; ++i) {
        const vfloat4 v = {vals[4 * i + 0], vals[4 * i + 1],
                           vals[4 * i + 2], vals[4 * i + 3]};
        __builtin_nontemporal_store(v, reinterpret_cast<vfloat4*>(op) + i);
    }
}

// ---------------- proven fallback path (round-0, 381 us) ----------------

__global__ __launch_bounds__(256, 8)
void hashgrid_level_kernel(const float* __restrict__ x,
                           const float* __restrict__ tables,
                           _Float16* __restrict__ ws)
{
    const int n = blockIdx.x * 256 + threadIdx.x;
    const int l = blockIdx.y;

    const float px = x[3 * n + 0];
    const float py = x[3 * n + 1];
    const float pz = x[3 * n + 2];

    const float2* __restrict__ tab =
        reinterpret_cast<const float2*>(tables) + (size_t)l * T;

    const float2 f = encode_one_level(px, py, pz, c_res[l], tab);
    vhalf2 h = {(_Float16)(f.x * WS_SCALE), (_Float16)(f.y * WS_SCALE)};
    __builtin_nontemporal_store(
        h, reinterpret_cast<vhalf2*>(ws) + ((size_t)l * NPTS + n));
}

__global__ __launch_bounds__(256)
void hashgrid_transpose_kernel(const _Float16* __restrict__ ws,
                               float* __restrict__ out)
{
    __shared__ float lds[512 * 25];
    const int t = threadIdx.x;
    const int base = blockIdx.x * 512;

#pragma unroll
    for (int l = 0; l < NLEVELS; ++l) {
#pragma unroll
        for (int k = 0; k < 2; ++k) {
            const int p = t + 256 * k;
            const vhalf2 h = __builtin_nontemporal_load(
                reinterpret_cast<const vhalf2*>(ws) + ((size_t)l * NPTS + base + p));
            lds[p * 25 + 2 * l + 0] = (float)h.x * WS_INV_SCALE;
            lds[p * 25 + 2 * l + 1] = (float)h.y * WS_INV_SCALE;
        }
    }
    __syncthreads();

    float* __restrict__ ob = out + (size_t)base * 24;
#pragma unroll
    for (int i = 0; i < 12; ++i) {
        const int j  = i * 256 + t;
        const int f0 = 4 * j;
        const int p  = f0 / 24;
        const int c  = f0 % 24;
        vfloat4 v = {lds[p * 25 + c + 0], lds[p * 25 + c + 1],
                     lds[p * 25 + c + 2], lds[p * 25 + c + 3]};
        __builtin_nontemporal_store(v, reinterpret_cast<vfloat4*>(ob + f0));
    }
}

__global__ __launch_bounds__(256, 4)
void hashgrid_fused_kernel(const float* __restrict__ x,
                           const float* __restrict__ tables,
                           float* __restrict__ out)
{
    const int n = blockIdx.x * 256 + threadIdx.x;
    const float px = x[3 * n + 0];
    const float py = x[3 * n + 1];
    const float pz = x[3 * n + 2];

    float o[2 * NLEVELS];
#pragma unroll
    for (int l = 0; l < NLEVELS; ++l) {
        const float2* __restrict__ tab =
            reinterpret_cast<const float2*>(tables) + (size_t)l * T;
        const float2 f = encode_one_level(px, py, pz, c_res[l], tab);
        o[2 * l + 0] = f.x;
        o[2 * l + 1] = f.y;
    }
    float4* __restrict__ op = reinterpret_cast<float4*>(out + (size_t)n * 24);
#pragma unroll
    for (int i = 0; i < 6; ++i)
        op[i] = make_float4(o[4*i+0], o[4*i+1], o[4*i+2], o[4*i+3]);
}

// ---------------- launch ----------------

extern "C" void kernel_launch(void* const* d_in, const int* in_sizes, int n_in,
                              void* d_out, int out_size, void* d_ws, size_t ws_size,
                              hipStream_t stream)
{
    const float* x      = reinterpret_cast<const float*>(d_in[0]);   // (N,3)
    const float* tables = reinterpret_cast<const float*>(d_in[1]);   // (12,T,2)
    float* out          = reinterpret_cast<float*>(d_out);           // (N,24)

    const size_t SZ_WS  = (size_t)NPTS * NLEVELS * 4;        // 48 MB tiled ws
    const size_t SZ_XS4 = (size_t)NPTS * 4 * sizeof(float);  // 16 MB
    const size_t SZ_O2S = (size_t)NPTS * sizeof(unsigned);   //  4 MB
    const size_t SZ_H   = (size_t)NBUCK * sizeof(unsigned);  // 128 KB
    const size_t need_sorted = SZ_WS + SZ_XS4 + SZ_O2S + 2 * SZ_H; // 71565312 B

    if (ws_size >= need_sorted) {
        char* p = reinterpret_cast<char*>(d_ws);
        unsigned* ws_dw  = reinterpret_cast<unsigned*>(p);  p += SZ_WS;
        vfloat4*  xs4    = reinterpret_cast<vfloat4*>(p);   p += SZ_XS4;
        unsigned* o2s    = reinterpret_cast<unsigned*>(p);  p += SZ_O2S;
        unsigned* hist   = reinterpret_cast<unsigned*>(p);  p += SZ_H;
        unsigned* cursor = reinterpret_cast<unsigned*>(p);

        hipMemsetAsync(hist, 0, SZ_H, stream);
        key_hist_kernel<<<NPTS / 256, 256, 0, stream>>>(x, hist);
        scan_kernel<<<1, 1024, 0, stream>>>(hist, cursor);
        scatter_kernel<<<NPTS / 256, 256, 0, stream>>>(x, cursor, xs4, o2s);
        gather_kernel<<<dim3(NPTS / 256, NLEVELS), 256, 0, stream>>>(
            xs4, tables, ws_dw);
        finish_kernel<<<NPTS / 256, 256, 0, stream>>>(ws_dw, o2s, out);
        return;
    }

    if (ws_size >= (size_t)NLEVELS * NPTS * 2 * sizeof(_Float16)) {
        _Float16* ws = reinterpret_cast<_Float16*>(d_ws);
        dim3 grid(NPTS / 256, NLEVELS);
        hashgrid_level_kernel<<<grid, 256, 0, stream>>>(x, tables, ws);
        hashgrid_transpose_kernel<<<NPTS / 512, 256, 0, stream>>>(ws, out);
        return;
    }

    hashgrid_fused_kernel<<<NPTS / 256, 256, 0, stream>>>(x, tables, out);
}

// Round 7
// 387.187 us; speedup vs baseline: 1.6108x; 1.6108x over previous
//
#include <hip/hip_runtime.h>

// HashGridEncoding: N=2^20 points, 12 levels, T=2^19 entries/level, F=2.
//
// Round-7 = round-6 resubmitted (bench container failed; experiment never ran).
// Round-5's failure was a transpose indexing bug (half-unit pointer
// arithmetic halved the ws offset), NOT the sc0 gathers. Transpose reverted
// to the round-0 proven code verbatim. The level pass is split to run a
// clean single-variable experiment on cache policy:
//   - levels 0-2  (table footprints 39/97/238 KB): plain loads -> keep their
//     L1 hits (L1=32KB absorbs much of these levels' traffic).
//   - levels 3-11 (footprint ~4MB each, L1 hit ~0): `sc0` loads = device-
//     coherent = L1 bypass. Under the L1-fill-BW model this cuts 64B fills
//     to 16B moves (fine pass -25..30%); under the L2-request-throughput
//     model it is neutral (still one L2 request slot per gather).
// Data returned is bit-identical either way -> absmax must return to 4.8e-7.

constexpr int NPTS     = 1 << 20;
constexpr int NLEVELS  = 12;
constexpr unsigned T     = 1u << 19;
constexpr unsigned TMASK = T - 1u;
constexpr unsigned P1 = 2654435761u;
constexpr unsigned P2 = 805459861u;

constexpr float WS_SCALE     = 16384.0f;          // 2^14, exact
constexpr float WS_INV_SCALE = 1.0f / 16384.0f;

typedef float    vfloat2 __attribute__((ext_vector_type(2)));
typedef float    vfloat4 __attribute__((ext_vector_type(4)));
typedef _Float16 vhalf2  __attribute__((ext_vector_type(2)));

// floor(16 * 1.38^l) for l=0..11 (verified in fp64)
__constant__ float c_res[NLEVELS] = {16.f, 22.f, 30.f, 42.f, 58.f, 80.f,
                                     110.f, 152.f, 210.f, 290.f, 400.f, 553.f};

// ---- L1-bypass gathers (sc0 = device-coherent: no L1 allocation, L2
//      replacement untouched). One asm block per corner group, single
//      vmcnt(0) at the end -> MLP preserved. ----

__device__ __forceinline__ void load4_x4_sc0(
    const vfloat4* a0, const vfloat4* a1, const vfloat4* a2, const vfloat4* a3,
    vfloat4& q0, vfloat4& q1, vfloat4& q2, vfloat4& q3)
{
    asm volatile(
        "global_load_dwordx4 %0, %4, off sc0\n\t"
        "global_load_dwordx4 %1, %5, off sc0\n\t"
        "global_load_dwordx4 %2, %6, off sc0\n\t"
        "global_load_dwordx4 %3, %7, off sc0\n\t"
        "s_waitcnt vmcnt(0)"
        : "=&v"(q0), "=&v"(q1), "=&v"(q2), "=&v"(q3)
        : "v"(a0), "v"(a1), "v"(a2), "v"(a3));
}

__device__ __forceinline__ void load8_x2_sc0(
    const vfloat2* a0, const vfloat2* a1, const vfloat2* a2, const vfloat2* a3,
    const vfloat2* a4, const vfloat2* a5, const vfloat2* a6, const vfloat2* a7,
    vfloat2& q0, vfloat2& q1, vfloat2& q2, vfloat2& q3,
    vfloat2& q4, vfloat2& q5, vfloat2& q6, vfloat2& q7)
{
    asm volatile(
        "global_load_dwordx2 %0, %8, off sc0\n\t"
        "global_load_dwordx2 %1, %9, off sc0\n\t"
        "global_load_dwordx2 %2, %10, off sc0\n\t"
        "global_load_dwordx2 %3, %11, off sc0\n\t"
        "global_load_dwordx2 %4, %12, off sc0\n\t"
        "global_load_dwordx2 %5, %13, off sc0\n\t"
        "global_load_dwordx2 %6, %14, off sc0\n\t"
        "global_load_dwordx2 %7, %15, off sc0\n\t"
        "s_waitcnt vmcnt(0)"
        : "=&v"(q0), "=&v"(q1), "=&v"(q2), "=&v"(q3),
          "=&v"(q4), "=&v"(q5), "=&v"(q6), "=&v"(q7)
        : "v"(a0), "v"(a1), "v"(a2), "v"(a3),
          "v"(a4), "v"(a5), "v"(a6), "v"(a7));
}

template <bool BYPASS>
__device__ __forceinline__ float2 encode_one_level(
    float px, float py, float pz, float r, const float2* __restrict__ tab)
{
    const float xs = px * r, ys = py * r, zs = pz * r;
    const float xf = floorf(xs), yf = floorf(ys), zf = floorf(zs);
    const float wx = xs - xf, wy = ys - yf, wz = zs - zf;
    const unsigned xi = (unsigned)xf, yi = (unsigned)yf, zi = (unsigned)zf;

    // Y hash component for the 4 (oy,oz) pairs; corner c = ox + 2*oy + 4*oz.
    unsigned Y[4];
#pragma unroll
    for (int j = 0; j < 4; ++j) {
        const unsigned oy = j & 1u, oz = (j >> 1) & 1u;
        Y[j] = ((yi + oy) * P1) ^ ((zi + oz) * P2);
    }

    float2 f[8];
    if ((xi & 1u) == 0u) {
        // even xi: corners (ox=0 -> h, ox=1 -> h^1) share one 16B-aligned pair
        unsigned h[4];
#pragma unroll
        for (int j = 0; j < 4; ++j) h[j] = (xi ^ Y[j]) & TMASK;

        vfloat4 q[4];
        if constexpr (BYPASS) {
            load4_x4_sc0(reinterpret_cast<const vfloat4*>(tab + (h[0] & ~1u)),
                         reinterpret_cast<const vfloat4*>(tab + (h[1] & ~1u)),
                         reinterpret_cast<const vfloat4*>(tab + (h[2] & ~1u)),
                         reinterpret_cast<const vfloat4*>(tab + (h[3] & ~1u)),
                         q[0], q[1], q[2], q[3]);
        } else {
#pragma unroll
            for (int j = 0; j < 4; ++j)
                q[j] = *reinterpret_cast<const vfloat4*>(tab + (h[j] & ~1u));
        }
#pragma unroll
        for (int j = 0; j < 4; ++j) {
            const bool hi = (h[j] & 1u) != 0u;   // entry h sits in high half?
            const float2 e_lo = make_float2(q[j].x, q[j].y);
            const float2 e_hi = make_float2(q[j].z, q[j].w);
            f[2 * j + 0] = hi ? e_hi : e_lo;     // ox=0 -> entry h
            f[2 * j + 1] = hi ? e_lo : e_hi;     // ox=1 -> entry h^1
        }
    } else {
        if constexpr (BYPASS) {
            const vfloat2* a[8];
#pragma unroll
            for (int j = 0; j < 4; ++j) {
                a[2 * j + 0] = reinterpret_cast<const vfloat2*>(
                    tab + ((xi ^ Y[j]) & TMASK));
                a[2 * j + 1] = reinterpret_cast<const vfloat2*>(
                    tab + (((xi + 1u) ^ Y[j]) & TMASK));
            }
            vfloat2 q[8];
            load8_x2_sc0(a[0], a[1], a[2], a[3], a[4], a[5], a[6], a[7],
                         q[0], q[1], q[2], q[3], q[4], q[5], q[6], q[7]);
#pragma unroll
            for (int c = 0; c < 8; ++c) f[c] = make_float2(q[c].x, q[c].y);
        } else {
#pragma unroll
            for (int j = 0; j < 4; ++j) {
                const unsigned h0 = (xi ^ Y[j]) & TMASK;
                const unsigned h1 = ((xi + 1u) ^ Y[j]) & TMASK;
                f[2 * j + 0] = tab[h0];
                f[2 * j + 1] = tab[h1];
            }
        }
    }

    // accumulation order identical to reference (c = 0..7) -> bit-stable
    float f0 = 0.f, f1 = 0.f;
#pragma unroll
    for (int c = 0; c < 8; ++c) {
        const unsigned ox = c & 1u, oy = (c >> 1) & 1u, oz = (c >> 2) & 1u;
        const float w = (ox ? wx : 1.f - wx) *
                        (oy ? wy : 1.f - wy) *
                        (oz ? wz : 1.f - wz);
        f0 += w * f[c].x;
        f1 += w * f[c].y;
    }
    return make_float2(f0, f1);
}

// Phase 1: grid (NPTS/256, NL), 1 point/thread. Level = LBASE + blockIdx.y.
// ws layout: (L, N) half2 -> wave writes 256B full lines.
template <int LBASE, bool BYPASS>
__global__ __launch_bounds__(256, 8)
void hashgrid_level_kernel(const float* __restrict__ x,
                           const float* __restrict__ tables,
                           _Float16* __restrict__ ws)
{
    const int n = blockIdx.x * 256 + threadIdx.x;
    const int l = LBASE + blockIdx.y;

    const float px = x[3 * n + 0];
    const float py = x[3 * n + 1];
    const float pz = x[3 * n + 2];

    const float2* __restrict__ tab =
        reinterpret_cast<const float2*>(tables) + (size_t)l * T;

    const float2 f = encode_one_level<BYPASS>(px, py, pz, c_res[l], tab);
    vhalf2 h = {(_Float16)(f.x * WS_SCALE), (_Float16)(f.y * WS_SCALE)};
    __builtin_nontemporal_store(
        h, reinterpret_cast<vhalf2*>(ws) + ((size_t)l * NPTS + n));
}

// Phase 2 (round-0 proven code, verbatim): (L,N) half2 -> (N, L*2) fp32.
// 512 points/block; thread t handles rows t and t+256 (LDS stride 25 odd ->
// conflict-free). Global writes are lane-contiguous full-line float4s.
__global__ __launch_bounds__(256)
void hashgrid_transpose_kernel(const _Float16* __restrict__ ws,
                               float* __restrict__ out)
{
    __shared__ float lds[512 * 25];
    const int t = threadIdx.x;
    const int base = blockIdx.x * 512;

#pragma unroll
    for (int l = 0; l < NLEVELS; ++l) {
#pragma unroll
        for (int k = 0; k < 2; ++k) {
            const int p = t + 256 * k;
            const vhalf2 h = __builtin_nontemporal_load(
                reinterpret_cast<const vhalf2*>(ws) + ((size_t)l * NPTS + base + p));
            lds[p * 25 + 2 * l + 0] = (float)h.x * WS_INV_SCALE;
            lds[p * 25 + 2 * l + 1] = (float)h.y * WS_INV_SCALE;
        }
    }
    __syncthreads();

    // Block's output region: 512*24 floats = 3072 float4, lane-contiguous.
    float* __restrict__ ob = out + (size_t)base * 24;
#pragma unroll
    for (int i = 0; i < 12; ++i) {
        const int j  = i * 256 + t;   // float4 index within block
        const int f0 = 4 * j;         // flat float offset
        const int p  = f0 / 24;       // local point
        const int c  = f0 % 24;       // component (multiple of 4)
        vfloat4 v = {lds[p * 25 + c + 0], lds[p * 25 + c + 1],
                     lds[p * 25 + c + 2], lds[p * 25 + c + 3]};
        __builtin_nontemporal_store(v, reinterpret_cast<vfloat4*>(ob + f0));
    }
}

// Fallback (ws too small): point-major fused kernel, direct (N,24) writes.
__global__ __launch_bounds__(256, 4)
void hashgrid_fused_kernel(const float* __restrict__ x,
                           const float* __restrict__ tables,
                           float* __restrict__ out)
{
    const int n = blockIdx.x * 256 + threadIdx.x;
    const float px = x[3 * n + 0];
    const float py = x[3 * n + 1];
    const float pz = x[3 * n + 2];

    float o[2 * NLEVELS];
#pragma unroll
    for (int l = 0; l < NLEVELS; ++l) {
        const float2* __restrict__ tab =
            reinterpret_cast<const float2*>(tables) + (size_t)l * T;
        const float2 f = encode_one_level<false>(px, py, pz, c_res[l], tab);
        o[2 * l + 0] = f.x;
        o[2 * l + 1] = f.y;
    }
    float4* __restrict__ op = reinterpret_cast<float4*>(out + (size_t)n * 24);
#pragma unroll
    for (int i = 0; i < 6; ++i)
        op[i] = make_float4(o[4*i+0], o[4*i+1], o[4*i+2], o[4*i+3]);
}

extern "C" void kernel_launch(void* const* d_in, const int* in_sizes, int n_in,
                              void* d_out, int out_size, void* d_ws, size_t ws_size,
                              hipStream_t stream)
{
    const float* x      = reinterpret_cast<const float*>(d_in[0]);   // (N,3)
    const float* tables = reinterpret_cast<const float*>(d_in[1]);   // (12,T,2)
    float* out          = reinterpret_cast<float*>(d_out);           // (N,24)

    const size_t ws_needed = (size_t)NLEVELS * NPTS * 2 * sizeof(_Float16); // ~50MB
    if (ws_size >= ws_needed) {
        _Float16* ws = reinterpret_cast<_Float16*>(d_ws);
        // coarse levels 0-2: plain loads (keep L1 hits)
        hashgrid_level_kernel<0, false>
            <<<dim3(NPTS / 256, 3), 256, 0, stream>>>(x, tables, ws);
        // fine levels 3-11: sc0 L1-bypass loads
        hashgrid_level_kernel<3, true>
            <<<dim3(NPTS / 256, 9), 256, 0, stream>>>(x, tables, ws);
        hashgrid_transpose_kernel<<<NPTS / 512, 256, 0, stream>>>(ws, out);
    } else {
        hashgrid_fused_kernel<<<NPTS / 256, 256, 0, stream>>>(x, tables, out);
    }
}

// Round 8
// 380.594 us; speedup vs baseline: 1.6387x; 1.0173x over previous
//
#include <hip/hip_runtime.h>

// HashGridEncoding: N=2^20 points, 12 levels, T=2^19 entries/level, F=2.
//
// Round-8. Established: the fine-level gather is L2-request-throughput bound
// (~0.5 req/cyc/CU; sc0 A/B was neutral -> request count, not bytes, is the
// cost; request count is already minimal for this hash). Sort does not pay
// (prelude+permutation tax > merge savings, rounds 2-4). So the gather
// (~205us for levels 3-11) is kept as-is (proven sc0 kernel, 204.5us), and
// this round attacks the ~135us backend:
//   - levels 0-2 (tables 39/97/238 KB, L1/L2-resident) are computed INLINE
//     in the finalize kernel (fp32 direct to LDS -> more accurate than the
//     fp16 ws round-trip), overlapping the 132MB transpose stream.
//   - deletes: coarse level dispatch (~45us), 24MB ws round-trip, 1 launch.
//   - ws read path for levels 3-11 and the store phase are byte-identical
//     to the round-0 proven transpose.

constexpr int NPTS     = 1 << 20;
constexpr int NLEVELS  = 12;
constexpr unsigned T     = 1u << 19;
constexpr unsigned TMASK = T - 1u;
constexpr unsigned P1 = 2654435761u;
constexpr unsigned P2 = 805459861u;

constexpr float WS_SCALE     = 16384.0f;          // 2^14, exact
constexpr float WS_INV_SCALE = 1.0f / 16384.0f;

typedef float    vfloat2 __attribute__((ext_vector_type(2)));
typedef float    vfloat4 __attribute__((ext_vector_type(4)));
typedef _Float16 vhalf2  __attribute__((ext_vector_type(2)));

// floor(16 * 1.38^l) for l=0..11 (verified in fp64)
__constant__ float c_res[NLEVELS] = {16.f, 22.f, 30.f, 42.f, 58.f, 80.f,
                                     110.f, 152.f, 210.f, 290.f, 400.f, 553.f};

// ---- L1-bypass gathers (sc0 = device-coherent: no L1 allocation, L2
//      replacement untouched). Proven neutral-vs-plain on fine levels
//      (round-7 A/B); kept for the fine kernel as the harness-proven path. ----

__device__ __forceinline__ void load4_x4_sc0(
    const vfloat4* a0, const vfloat4* a1, const vfloat4* a2, const vfloat4* a3,
    vfloat4& q0, vfloat4& q1, vfloat4& q2, vfloat4& q3)
{
    asm volatile(
        "global_load_dwordx4 %0, %4, off sc0\n\t"
        "global_load_dwordx4 %1, %5, off sc0\n\t"
        "global_load_dwordx4 %2, %6, off sc0\n\t"
        "global_load_dwordx4 %3, %7, off sc0\n\t"
        "s_waitcnt vmcnt(0)"
        : "=&v"(q0), "=&v"(q1), "=&v"(q2), "=&v"(q3)
        : "v"(a0), "v"(a1), "v"(a2), "v"(a3));
}

__device__ __forceinline__ void load8_x2_sc0(
    const vfloat2* a0, const vfloat2* a1, const vfloat2* a2, const vfloat2* a3,
    const vfloat2* a4, const vfloat2* a5, const vfloat2* a6, const vfloat2* a7,
    vfloat2& q0, vfloat2& q1, vfloat2& q2, vfloat2& q3,
    vfloat2& q4, vfloat2& q5, vfloat2& q6, vfloat2& q7)
{
    asm volatile(
        "global_load_dwordx2 %0, %8, off sc0\n\t"
        "global_load_dwordx2 %1, %9, off sc0\n\t"
        "global_load_dwordx2 %2, %10, off sc0\n\t"
        "global_load_dwordx2 %3, %11, off sc0\n\t"
        "global_load_dwordx2 %4, %12, off sc0\n\t"
        "global_load_dwordx2 %5, %13, off sc0\n\t"
        "global_load_dwordx2 %6, %14, off sc0\n\t"
        "global_load_dwordx2 %7, %15, off sc0\n\t"
        "s_waitcnt vmcnt(0)"
        : "=&v"(q0), "=&v"(q1), "=&v"(q2), "=&v"(q3),
          "=&v"(q4), "=&v"(q5), "=&v"(q6), "=&v"(q7)
        : "v"(a0), "v"(a1), "v"(a2), "v"(a3),
          "v"(a4), "v"(a5), "v"(a6), "v"(a7));
}

template <bool BYPASS>
__device__ __forceinline__ float2 encode_one_level(
    float px, float py, float pz, float r, const float2* __restrict__ tab)
{
    const float xs = px * r, ys = py * r, zs = pz * r;
    const float xf = floorf(xs), yf = floorf(ys), zf = floorf(zs);
    const float wx = xs - xf, wy = ys - yf, wz = zs - zf;
    const unsigned xi = (unsigned)xf, yi = (unsigned)yf, zi = (unsigned)zf;

    // Y hash component for the 4 (oy,oz) pairs; corner c = ox + 2*oy + 4*oz.
    unsigned Y[4];
#pragma unroll
    for (int j = 0; j < 4; ++j) {
        const unsigned oy = j & 1u, oz = (j >> 1) & 1u;
        Y[j] = ((yi + oy) * P1) ^ ((zi + oz) * P2);
    }

    float2 f[8];
    if ((xi & 1u) == 0u) {
        // even xi: corners (ox=0 -> h, ox=1 -> h^1) share one 16B-aligned pair
        unsigned h[4];
#pragma unroll
        for (int j = 0; j < 4; ++j) h[j] = (xi ^ Y[j]) & TMASK;

        vfloat4 q[4];
        if constexpr (BYPASS) {
            load4_x4_sc0(reinterpret_cast<const vfloat4*>(tab + (h[0] & ~1u)),
                         reinterpret_cast<const vfloat4*>(tab + (h[1] & ~1u)),
                         reinterpret_cast<const vfloat4*>(tab + (h[2] & ~1u)),
                         reinterpret_cast<const vfloat4*>(tab + (h[3] & ~1u)),
                         q[0], q[1], q[2], q[3]);
        } else {
#pragma unroll
            for (int j = 0; j < 4; ++j)
                q[j] = *reinterpret_cast<const vfloat4*>(tab + (h[j] & ~1u));
        }
#pragma unroll
        for (int j = 0; j < 4; ++j) {
            const bool hi = (h[j] & 1u) != 0u;   // entry h sits in high half?
            const float2 e_lo = make_float2(q[j].x, q[j].y);
            const float2 e_hi = make_float2(q[j].z, q[j].w);
            f[2 * j + 0] = hi ? e_hi : e_lo;     // ox=0 -> entry h
            f[2 * j + 1] = hi ? e_lo : e_hi;     // ox=1 -> entry h^1
        }
    } else {
        if constexpr (BYPASS) {
            const vfloat2* a[8];
#pragma unroll
            for (int j = 0; j < 4; ++j) {
                a[2 * j + 0] = reinterpret_cast<const vfloat2*>(
                    tab + ((xi ^ Y[j]) & TMASK));
                a[2 * j + 1] = reinterpret_cast<const vfloat2*>(
                    tab + (((xi + 1u) ^ Y[j]) & TMASK));
            }
            vfloat2 q[8];
            load8_x2_sc0(a[0], a[1], a[2], a[3], a[4], a[5], a[6], a[7],
                         q[0], q[1], q[2], q[3], q[4], q[5], q[6], q[7]);
#pragma unroll
            for (int c = 0; c < 8; ++c) f[c] = make_float2(q[c].x, q[c].y);
        } else {
#pragma unroll
            for (int j = 0; j < 4; ++j) {
                const unsigned h0 = (xi ^ Y[j]) & TMASK;
                const unsigned h1 = ((xi + 1u) ^ Y[j]) & TMASK;
                f[2 * j + 0] = tab[h0];
                f[2 * j + 1] = tab[h1];
            }
        }
    }

    // accumulation order identical to reference (c = 0..7) -> bit-stable
    float f0 = 0.f, f1 = 0.f;
#pragma unroll
    for (int c = 0; c < 8; ++c) {
        const unsigned ox = c & 1u, oy = (c >> 1) & 1u, oz = (c >> 2) & 1u;
        const float w = (ox ? wx : 1.f - wx) *
                        (oy ? wy : 1.f - wy) *
                        (oz ? wz : 1.f - wz);
        f0 += w * f[c].x;
        f1 += w * f[c].y;
    }
    return make_float2(f0, f1);
}

// Phase 1: FINE levels only. grid (NPTS/256, 9), level = 3 + blockIdx.y.
// Proven round-7 kernel (204.5us): sc0 L1-bypass gathers, (L,N) half2 ws.
__global__ __launch_bounds__(256, 8)
void hashgrid_level_kernel(const float* __restrict__ x,
                           const float* __restrict__ tables,
                           _Float16* __restrict__ ws)
{
    const int n = blockIdx.x * 256 + threadIdx.x;
    const int l = 3 + blockIdx.y;

    const float px = x[3 * n + 0];
    const float py = x[3 * n + 1];
    const float pz = x[3 * n + 2];

    const float2* __restrict__ tab =
        reinterpret_cast<const float2*>(tables) + (size_t)l * T;

    const float2 f = encode_one_level<true>(px, py, pz, c_res[l], tab);
    vhalf2 h = {(_Float16)(f.x * WS_SCALE), (_Float16)(f.y * WS_SCALE)};
    __builtin_nontemporal_store(
        h, reinterpret_cast<vhalf2*>(ws) + ((size_t)l * NPTS + n));
}

// Phase 2: finalize = transpose (levels 3-11 from ws, round-0 proven code)
// + inline coarse levels 0-2 (plain loads, tables L1/L2-resident, fp32
// straight to LDS -- no fp16 quantization for these levels).
// 512 points/block; thread t handles rows t and t+256 (LDS stride 25 odd ->
// conflict-free). Global writes are lane-contiguous full-line float4s.
__global__ __launch_bounds__(256)
void hashgrid_finalize_kernel(const float* __restrict__ x,
                              const float* __restrict__ tables,
                              const _Float16* __restrict__ ws,
                              float* __restrict__ out)
{
    __shared__ float lds[512 * 25];
    const int t = threadIdx.x;
    const int base = blockIdx.x * 512;

    // fine levels 3-11 from ws (byte-identical to round-0 transpose reads)
#pragma unroll
    for (int l = 3; l < NLEVELS; ++l) {
#pragma unroll
        for (int k = 0; k < 2; ++k) {
            const int p = t + 256 * k;
            const vhalf2 h = __builtin_nontemporal_load(
                reinterpret_cast<const vhalf2*>(ws) + ((size_t)l * NPTS + base + p));
            lds[p * 25 + 2 * l + 0] = (float)h.x * WS_INV_SCALE;
            lds[p * 25 + 2 * l + 1] = (float)h.y * WS_INV_SCALE;
        }
    }

    // coarse levels 0-2 computed inline (gathers hit L1/L2; overlaps stream)
#pragma unroll
    for (int k = 0; k < 2; ++k) {
        const int p = t + 256 * k;
        const int n = base + p;
        const float px = x[3 * n + 0];
        const float py = x[3 * n + 1];
        const float pz = x[3 * n + 2];
#pragma unroll
        for (int l = 0; l < 3; ++l) {
            const float2* __restrict__ tab =
                reinterpret_cast<const float2*>(tables) + (size_t)l * T;
            const float2 f = encode_one_level<false>(px, py, pz, c_res[l], tab);
            lds[p * 25 + 2 * l + 0] = f.x;   // stride 25 odd -> conflict-free
            lds[p * 25 + 2 * l + 1] = f.y;
        }
    }
    __syncthreads();

    // Block's output region: 512*24 floats = 3072 float4, lane-contiguous.
    float* __restrict__ ob = out + (size_t)base * 24;
#pragma unroll
    for (int i = 0; i < 12; ++i) {
        const int j  = i * 256 + t;   // float4 index within block
        const int f0 = 4 * j;         // flat float offset
        const int p  = f0 / 24;       // local point
        const int c  = f0 % 24;       // component (multiple of 4)
        vfloat4 v = {lds[p * 25 + c + 0], lds[p * 25 + c + 1],
                     lds[p * 25 + c + 2], lds[p * 25 + c + 3]};
        __builtin_nontemporal_store(v, reinterpret_cast<vfloat4*>(ob + f0));
    }
}

// Fallback (ws too small): point-major fused kernel, direct (N,24) writes.
__global__ __launch_bounds__(256, 4)
void hashgrid_fused_kernel(const float* __restrict__ x,
                           const float* __restrict__ tables,
                           float* __restrict__ out)
{
    const int n = blockIdx.x * 256 + threadIdx.x;
    const float px = x[3 * n + 0];
    const float py = x[3 * n + 1];
    const float pz = x[3 * n + 2];

    float o[2 * NLEVELS];
#pragma unroll
    for (int l = 0; l < NLEVELS; ++l) {
        const float2* __restrict__ tab =
            reinterpret_cast<const float2*>(tables) + (size_t)l * T;
        const float2 f = encode_one_level<false>(px, py, pz, c_res[l], tab);
        o[2 * l + 0] = f.x;
        o[2 * l + 1] = f.y;
    }
    float4* __restrict__ op = reinterpret_cast<float4*>(out + (size_t)n * 24);
#pragma unroll
    for (int i = 0; i < 6; ++i)
        op[i] = make_float4(o[4*i+0], o[4*i+1], o[4*i+2], o[4*i+3]);
}

extern "C" void kernel_launch(void* const* d_in, const int* in_sizes, int n_in,
                              void* d_out, int out_size, void* d_ws, size_t ws_size,
                              hipStream_t stream)
{
    const float* x      = reinterpret_cast<const float*>(d_in[0]);   // (N,3)
    const float* tables = reinterpret_cast<const float*>(d_in[1]);   // (12,T,2)
    float* out          = reinterpret_cast<float*>(d_out);           // (N,24)

    const size_t ws_needed = (size_t)NLEVELS * NPTS * 2 * sizeof(_Float16); // ~50MB
    if (ws_size >= ws_needed) {
        _Float16* ws = reinterpret_cast<_Float16*>(d_ws);
        // fine levels 3-11 (L2-request-bound roofline, proven 204.5us)
        hashgrid_level_kernel
            <<<dim3(NPTS / 256, 9), 256, 0, stream>>>(x, tables, ws);
        // transpose + inline coarse levels 0-2
        hashgrid_finalize_kernel
            <<<NPTS / 512, 256, 0, stream>>>(x, tables, ws, out);
    } else {
        hashgrid_fused_kernel<<<NPTS / 256, 256, 0, stream>>>(x, tables, out);
    }
}